// Round 1
// 1744.781 us; speedup vs baseline: 1.5270x; 1.5270x over previous
//
#include <hip/hip_runtime.h>
#include <hip/hip_bf16.h>
#include <math.h>

// Problem constants (from reference)
constexpr int E_EXP = 32;
constexpr int TOPK  = 4;
constexpr int H_DIM = 2048;
constexpr int I_DIM = 2048;
constexpr int T_TOK = 512;
constexpr int CAP   = 256;
constexpr int TWOI  = 4096;           // 2*I
constexpr int NPAIR = T_TOK * TOPK;   // 2048
constexpr float ALPHA = 1.702f;
constexpr float LIMIT = 7.0f;

// NOTE (harness contract): integer inputs arrive as int32 per element.
// gate_up_proj / down_proj are int32 arrays of values in [-127,127].

typedef int v4i  __attribute__((ext_vector_type(4)));
typedef int v16i __attribute__((ext_vector_type(16)));

__device__ __forceinline__ float waveReduceMax(float v) {
    #pragma unroll
    for (int off = 32; off > 0; off >>= 1)
        v = fmaxf(v, __shfl_xor(v, off, 64));
    return v;
}

// ---------------------------------------------------------------------------
// Router: softmax + top-4 + renormalize. One thread per token.
// ---------------------------------------------------------------------------
__global__ void k_router(const float* __restrict__ logits,
                         int* __restrict__ topk_ids,
                         float* __restrict__ topk_w) {
    int t = blockIdx.x * blockDim.x + threadIdx.x;
    if (t >= T_TOK) return;
    float l[E_EXP];
    float mx = -1e30f;
    #pragma unroll
    for (int e = 0; e < E_EXP; e++) { l[e] = logits[t * E_EXP + e]; mx = fmaxf(mx, l[e]); }
    #pragma unroll
    for (int e = 0; e < E_EXP; e++) { l[e] = expf(l[e] - mx); }

    float v[TOPK]; int id[TOPK];
    #pragma unroll
    for (int k = 0; k < TOPK; k++) {
        float best = -1.0f; int bi = 0;
        #pragma unroll
        for (int e = 0; e < E_EXP; e++) {
            bool taken = false;
            for (int j = 0; j < k; j++) taken = taken || (id[j] == e);
            if (!taken && l[e] > best) { best = l[e]; bi = e; }
        }
        v[k] = best; id[k] = bi;
    }
    float inv = 1.0f / (v[0] + v[1] + v[2] + v[3]);
    #pragma unroll
    for (int k = 0; k < TOPK; k++) {
        topk_ids[t * TOPK + k] = id[k];
        topk_w[t * TOPK + k]   = v[k] * inv;
    }
}

// ---------------------------------------------------------------------------
// Per-token symmetric int8 dynamic quant of hidden_states. One block per token.
// ---------------------------------------------------------------------------
__global__ void k_quant_x(const float* __restrict__ x,
                          signed char* __restrict__ qx,
                          float* __restrict__ xs) {
    int t = blockIdx.x, tid = threadIdx.x;
    const float4* xr = (const float4*)(x + (size_t)t * H_DIM);
    float4 v0 = xr[tid * 2], v1 = xr[tid * 2 + 1];
    float am = fmaxf(fmaxf(fmaxf(fabsf(v0.x), fabsf(v0.y)), fmaxf(fabsf(v0.z), fabsf(v0.w))),
                     fmaxf(fmaxf(fabsf(v1.x), fabsf(v1.y)), fmaxf(fabsf(v1.z), fabsf(v1.w))));
    __shared__ float red[4];
    am = waveReduceMax(am);
    if ((tid & 63) == 0) red[tid >> 6] = am;
    __syncthreads();
    am = fmaxf(fmaxf(red[0], red[1]), fmaxf(red[2], red[3]));
    float s = am * (1.0f / 127.0f);
    if (tid == 0) xs[t] = s;
    float vv[8] = {v0.x, v0.y, v0.z, v0.w, v1.x, v1.y, v1.z, v1.w};
    int out[2]; signed char* ob = (signed char*)out;
    #pragma unroll
    for (int j = 0; j < 8; j++) {
        float q = (s > 0.f) ? rintf(vv[j] / s) : 0.f;   // bit-match round(x/s)
        q = fminf(127.f, fmaxf(-127.f, q));
        ob[j] = (signed char)q;
    }
    ((int2*)(qx + (size_t)t * H_DIM))[tid] = *(int2*)out;
}

// ---------------------------------------------------------------------------
// Dispatch: exact-order per-expert positions via ballot scan. One wave/expert.
// ---------------------------------------------------------------------------
__global__ void k_dispatch(const int* __restrict__ topk_ids,
                           int* __restrict__ pair_pos,
                           int* __restrict__ rows_map,
                           int* __restrict__ counts) {
    int e = blockIdx.x;
    int lane = threadIdx.x;
    int base = 0;
    unsigned long long lt = (1ull << lane) - 1ull;
    if (lane == 63) lt = 0x7FFFFFFFFFFFFFFFull;
    for (int i0 = 0; i0 < NPAIR; i0 += 64) {
        int idx = i0 + lane;
        int ee = topk_ids[idx];
        bool m = (ee == e);
        unsigned long long mask = __ballot(m);
        int pre = __popcll(mask & lt);
        if (m) {
            int pos = base + pre;
            pair_pos[idx] = pos;
            if (pos < CAP) rows_map[e * CAP + pos] = idx;
        }
        base += __popcll(mask);
    }
    if (lane == 0) counts[e] = (base < CAP) ? base : CAP;
}

// Exclusive scan of 32 counts (single thread — trivial).
__global__ void k_scan(const int* __restrict__ counts, int* __restrict__ offs) {
    if (threadIdx.x == 0 && blockIdx.x == 0) {
        int a = 0;
        for (int e = 0; e < E_EXP; e++) { offs[e] = a; a += counts[e]; }
        offs[E_EXP] = a;
    }
}

// ---------------------------------------------------------------------------
// MFMA grouped GEMM core: 128x64 tile per block, K-chunks of 64.
// A (activations int8) staged to LDS rows of 64B (stride 80).
// B (weights int32) loaded coalesced, packed to int8 k-runs in registers
// (4x4 byte transpose), staged to LDS [n][k] (stride 80).
// 4 waves = 2x2; each wave: two 32x32 mfma tiles (64 rows x 32 cols).
// ---------------------------------------------------------------------------
#define MT 128
#define NT 64
#define KC 64
#define LSTR 80   // LDS row stride in bytes (16B aligned, non-pow2 bank walk)

// GEMM1: [rows,H] x [H,2I] + dequant + bias + swiglu -> act f32 [rows_compact, I]
__global__ __launch_bounds__(256, 4) void k_gemm1(
    const signed char* __restrict__ qx, const float* __restrict__ xs,
    const int* __restrict__ W, const float* __restrict__ wscale,
    const float* __restrict__ wbias, const int* __restrict__ rows_map,
    const int* __restrict__ counts, const int* __restrict__ offs,
    float* __restrict__ act) {
    int e = blockIdx.z;
    int cnt = counts[e];
    int m0 = blockIdx.y * MT;
    if (m0 >= cnt) return;
    int rb = offs[e];
    int n0 = blockIdx.x * NT;
    int tid = threadIdx.x;

    __shared__ __align__(16) signed char a_lds[MT * LSTR];
    __shared__ __align__(16) signed char b_lds[NT * LSTR];
    __shared__ int   asrc_lds[MT];
    __shared__ float s_lds[MT];

    if (tid < MT) {
        int r = m0 + tid;
        int tok = 0; float sc = 0.f;
        if (r < cnt) { int pair = rows_map[e * CAP + r]; tok = pair >> 2; sc = xs[tok]; }
        asrc_lds[tid] = tok; s_lds[tid] = sc;
    }
    __syncthreads();

    // A staging: 4 threads per row, 16B each; rows tid>>2 and tid>>2 + 64.
    int arow = tid >> 2, ahalf = tid & 3;
    const signed char* ap0 = qx + (size_t)asrc_lds[arow]      * H_DIM + ahalf * 16;
    const signed char* ap1 = qx + (size_t)asrc_lds[arow + 64] * H_DIM + ahalf * 16;
    signed char* aw0 = a_lds + arow * LSTR + ahalf * 16;
    signed char* aw1 = a_lds + (arow + 64) * LSTR + ahalf * 16;

    // B staging: thread = (n-quad nq, k-quad kq); 4 coalesced dwordx4 loads,
    // 4x4 byte transpose in registers, 4 ds_write_b32.
    int nq = tid & 15, kq = tid >> 4;   // nq 0..15, kq 0..15
    const int* bp = W + (size_t)e * H_DIM * TWOI + (size_t)(kq * 4) * TWOI + n0 + nq * 4;
    int* bw = (int*)(b_lds + (nq * 4) * LSTR) + kq;   // + p*20 per n

    // wave decomposition: 2x2 waves, each 64 rows x 32 cols
    int lane = tid & 63, wv = tid >> 6;
    int wr = wv >> 1, wc = wv & 1;
    int l31 = lane & 31, lhi = lane >> 5;
    const signed char* ar = a_lds + (wr * 64 + l31) * LSTR + lhi * 16;
    const signed char* br = b_lds + (wc * 32 + l31) * LSTR + lhi * 16;

    v16i acc0 = {}, acc1 = {};

    for (int k0 = 0; k0 < H_DIM; k0 += KC) {
        int4 va0 = *(const int4*)ap0;
        int4 va1 = *(const int4*)ap1;
        int4 w0 = *(const int4*)(bp);
        int4 w1 = *(const int4*)(bp + TWOI);
        int4 w2 = *(const int4*)(bp + 2 * TWOI);
        int4 w3 = *(const int4*)(bp + 3 * TWOI);
        ap0 += KC; ap1 += KC; bp += (size_t)KC * TWOI;

        *(int4*)aw0 = va0;
        *(int4*)aw1 = va1;
        bw[0]      = (w0.x & 255) | ((w1.x & 255) << 8) | ((w2.x & 255) << 16) | (w3.x << 24);
        bw[20]     = (w0.y & 255) | ((w1.y & 255) << 8) | ((w2.y & 255) << 16) | (w3.y << 24);
        bw[40]     = (w0.z & 255) | ((w1.z & 255) << 8) | ((w2.z & 255) << 16) | (w3.z << 24);
        bw[60]     = (w0.w & 255) | ((w1.w & 255) << 8) | ((w2.w & 255) << 16) | (w3.w << 24);
        __syncthreads();

        #pragma unroll
        for (int kk = 0; kk < 2; kk++) {
            v4i bf = *(const v4i*)(br + kk * 32);
            v4i a0 = *(const v4i*)(ar + kk * 32);
            v4i a1 = *(const v4i*)(ar + 32 * LSTR + kk * 32);
            acc0 = __builtin_amdgcn_mfma_i32_32x32x32_i8(a0, bf, acc0, 0, 0, 0);
            acc1 = __builtin_amdgcn_mfma_i32_32x32x32_i8(a1, bf, acc1, 0, 0, 0);
        }
        __syncthreads();
    }

    // epilogue: dequant + bias + swiglu (interleaved cols), write act f32.
    // C/D layout (32x32): col = lane&31, row = (reg&3) + 8*(reg>>2) + 4*(lane>>5)
    int c = n0 + wc * 32 + l31;
    float wsc = wscale[e * TWOI + c];
    float wbs = wbias[e * TWOI + c];
    bool evenc = (l31 & 1) == 0;
    #pragma unroll
    for (int i = 0; i < 2; i++) {
        #pragma unroll
        for (int reg = 0; reg < 16; reg++) {
            int row_local = wr * 64 + i * 32 + (reg & 3) + 8 * (reg >> 2) + 4 * lhi;
            int accv = (i == 0) ? acc0[reg] : acc1[reg];
            float val = (float)accv * s_lds[row_local] * wsc + wbs;
            float other = __shfl_xor(val, 1, 64);     // partner column (c^1)
            int r = m0 + row_local;
            if (evenc && r < cnt) {
                float g   = fminf(val, LIMIT);
                float lin = fminf(fmaxf(other, -LIMIT), LIMIT);
                float sig = 1.0f / (1.0f + expf(-ALPHA * g));
                act[(size_t)(rb + r) * I_DIM + (c >> 1)] = g * sig * (lin + 1.0f);
            }
        }
    }
}

// Per-row requant of act (compact rows). One block per (e, cap-slot).
__global__ void k_quant_act(const float* __restrict__ act,
                            const int* __restrict__ counts,
                            const int* __restrict__ offs,
                            signed char* __restrict__ aq,
                            float* __restrict__ as_) {
    int e = blockIdx.x / CAP, p = blockIdx.x % CAP;
    if (p >= counts[e]) return;
    int row = offs[e] + p;
    int tid = threadIdx.x;
    const float4* xr = (const float4*)(act + (size_t)row * I_DIM);
    float4 v0 = xr[tid * 2], v1 = xr[tid * 2 + 1];
    float am = fmaxf(fmaxf(fmaxf(fabsf(v0.x), fabsf(v0.y)), fmaxf(fabsf(v0.z), fabsf(v0.w))),
                     fmaxf(fmaxf(fabsf(v1.x), fabsf(v1.y)), fmaxf(fabsf(v1.z), fabsf(v1.w))));
    __shared__ float red[4];
    am = waveReduceMax(am);
    if ((tid & 63) == 0) red[tid >> 6] = am;
    __syncthreads();
    am = fmaxf(fmaxf(red[0], red[1]), fmaxf(red[2], red[3]));
    float s = am * (1.0f / 127.0f);
    if (tid == 0) as_[row] = s;
    float vv[8] = {v0.x, v0.y, v0.z, v0.w, v1.x, v1.y, v1.z, v1.w};
    int out[2]; signed char* ob = (signed char*)out;
    #pragma unroll
    for (int j = 0; j < 8; j++) {
        float q = (s > 0.f) ? rintf(vv[j] / s) : 0.f;
        q = fminf(127.f, fmaxf(-127.f, q));
        ob[j] = (signed char)q;
    }
    ((int2*)(aq + (size_t)row * I_DIM))[tid] = *(int2*)out;
}

// GEMM2: [rows,I] x [I,H] + dequant + bias -> dn_rows f32 [NPAIR, H]
__global__ __launch_bounds__(256, 4) void k_gemm2(
    const signed char* __restrict__ aq, const float* __restrict__ as_,
    const int* __restrict__ W, const float* __restrict__ wscale,
    const float* __restrict__ wbias, const int* __restrict__ rows_map,
    const int* __restrict__ counts, const int* __restrict__ offs,
    float* __restrict__ dn_rows) {
    int e = blockIdx.z;
    int cnt = counts[e];
    int m0 = blockIdx.y * MT;
    if (m0 >= cnt) return;
    int rb = offs[e];
    int n0 = blockIdx.x * NT;
    int tid = threadIdx.x;

    __shared__ __align__(16) signed char a_lds[MT * LSTR];
    __shared__ __align__(16) signed char b_lds[NT * LSTR];
    __shared__ int   asrc_lds[MT];
    __shared__ int   pair_lds[MT];
    __shared__ float s_lds[MT];

    if (tid < MT) {
        int r = m0 + tid;
        int src = rb; int pr = 0; float sc = 0.f;
        if (r < cnt) { src = rb + r; pr = rows_map[e * CAP + r]; sc = as_[rb + r]; }
        asrc_lds[tid] = src; pair_lds[tid] = pr; s_lds[tid] = sc;
    }
    __syncthreads();

    int arow = tid >> 2, ahalf = tid & 3;
    const signed char* ap0 = aq + (size_t)asrc_lds[arow]      * I_DIM + ahalf * 16;
    const signed char* ap1 = aq + (size_t)asrc_lds[arow + 64] * I_DIM + ahalf * 16;
    signed char* aw0 = a_lds + arow * LSTR + ahalf * 16;
    signed char* aw1 = a_lds + (arow + 64) * LSTR + ahalf * 16;

    int nq = tid & 15, kq = tid >> 4;
    const int* bp = W + (size_t)e * I_DIM * H_DIM + (size_t)(kq * 4) * H_DIM + n0 + nq * 4;
    int* bw = (int*)(b_lds + (nq * 4) * LSTR) + kq;

    int lane = tid & 63, wv = tid >> 6;
    int wr = wv >> 1, wc = wv & 1;
    int l31 = lane & 31, lhi = lane >> 5;
    const signed char* ar = a_lds + (wr * 64 + l31) * LSTR + lhi * 16;
    const signed char* br = b_lds + (wc * 32 + l31) * LSTR + lhi * 16;

    v16i acc0 = {}, acc1 = {};

    for (int k0 = 0; k0 < I_DIM; k0 += KC) {
        int4 va0 = *(const int4*)ap0;
        int4 va1 = *(const int4*)ap1;
        int4 w0 = *(const int4*)(bp);
        int4 w1 = *(const int4*)(bp + H_DIM);
        int4 w2 = *(const int4*)(bp + 2 * H_DIM);
        int4 w3 = *(const int4*)(bp + 3 * H_DIM);
        ap0 += KC; ap1 += KC; bp += (size_t)KC * H_DIM;

        *(int4*)aw0 = va0;
        *(int4*)aw1 = va1;
        bw[0]  = (w0.x & 255) | ((w1.x & 255) << 8) | ((w2.x & 255) << 16) | (w3.x << 24);
        bw[20] = (w0.y & 255) | ((w1.y & 255) << 8) | ((w2.y & 255) << 16) | (w3.y << 24);
        bw[40] = (w0.z & 255) | ((w1.z & 255) << 8) | ((w2.z & 255) << 16) | (w3.z << 24);
        bw[60] = (w0.w & 255) | ((w1.w & 255) << 8) | ((w2.w & 255) << 16) | (w3.w << 24);
        __syncthreads();

        #pragma unroll
        for (int kk = 0; kk < 2; kk++) {
            v4i bf = *(const v4i*)(br + kk * 32);
            v4i a0 = *(const v4i*)(ar + kk * 32);
            v4i a1 = *(const v4i*)(ar + 32 * LSTR + kk * 32);
            acc0 = __builtin_amdgcn_mfma_i32_32x32x32_i8(a0, bf, acc0, 0, 0, 0);
            acc1 = __builtin_amdgcn_mfma_i32_32x32x32_i8(a1, bf, acc1, 0, 0, 0);
        }
        __syncthreads();
    }

    int c = n0 + wc * 32 + l31;
    float wsc = wscale[e * H_DIM + c];
    float wbs = wbias[e * H_DIM + c];
    #pragma unroll
    for (int i = 0; i < 2; i++) {
        #pragma unroll
        for (int reg = 0; reg < 16; reg++) {
            int row_local = wr * 64 + i * 32 + (reg & 3) + 8 * (reg >> 2) + 4 * lhi;
            int r = m0 + row_local;
            if (r < cnt) {
                int accv = (i == 0) ? acc0[reg] : acc1[reg];
                float val = (float)accv * s_lds[row_local] * wsc + wbs;
                dn_rows[(size_t)pair_lds[row_local] * H_DIM + c] = val;
            }
        }
    }
}

// Finalize: out[t] = sum_k w[t,k] * dn_rows[t*K+k] (valid only). Block per token.
__global__ void k_finalize(const float* __restrict__ dn_rows,
                           const float* __restrict__ topk_w,
                           const int* __restrict__ pair_pos,
                           float* __restrict__ out) {
    int t = blockIdx.x, tid = threadIdx.x;
    int h = tid * 8;
    float acc[8] = {0, 0, 0, 0, 0, 0, 0, 0};
    #pragma unroll
    for (int k = 0; k < TOPK; k++) {
        int pair = t * TOPK + k;
        if (pair_pos[pair] < CAP) {
            float w = topk_w[pair];
            const float4* dr = (const float4*)(dn_rows + (size_t)pair * H_DIM + h);
            float4 d0 = dr[0], d1 = dr[1];
            acc[0] += w * d0.x; acc[1] += w * d0.y; acc[2] += w * d0.z; acc[3] += w * d0.w;
            acc[4] += w * d1.x; acc[5] += w * d1.y; acc[6] += w * d1.z; acc[7] += w * d1.w;
        }
    }
    float4* o = (float4*)(out + (size_t)t * H_DIM + h);
    o[0] = make_float4(acc[0], acc[1], acc[2], acc[3]);
    o[1] = make_float4(acc[4], acc[5], acc[6], acc[7]);
}

// ---------------------------------------------------------------------------
extern "C" void kernel_launch(void* const* d_in, const int* in_sizes, int n_in,
                              void* d_out, int out_size, void* d_ws, size_t ws_size,
                              hipStream_t stream) {
    const float* hidden  = (const float*)d_in[0];
    const float* rlogits = (const float*)d_in[1];
    const int*   gup     = (const int*)d_in[2];    // int8 values stored as int32
    const float* gup_s   = (const float*)d_in[3];
    const float* gup_b   = (const float*)d_in[4];
    const int*   dnw     = (const int*)d_in[5];    // int8 values stored as int32
    const float* dn_s    = (const float*)d_in[6];
    const float* dn_b    = (const float*)d_in[7];
    float*       out     = (float*)d_out;

    char* ws = (char*)d_ws;
    size_t off = 0;
    auto alloc = [&](size_t bytes) -> void* {
        void* p = ws + off;
        off = (off + bytes + 255) & ~(size_t)255;
        return p;
    };
    signed char* qx       = (signed char*)alloc((size_t)T_TOK * H_DIM);          // 1 MB
    float*       xs       = (float*)alloc((size_t)T_TOK * 4);
    int*         topk_ids = (int*)alloc((size_t)NPAIR * 4);
    float*       topk_w   = (float*)alloc((size_t)NPAIR * 4);
    int*         pair_pos = (int*)alloc((size_t)NPAIR * 4);
    int*         rows_map = (int*)alloc((size_t)E_EXP * CAP * 4);
    int*         counts   = (int*)alloc((size_t)E_EXP * 4);
    int*         offs     = (int*)alloc((size_t)(E_EXP + 1) * 4);
    float*       act      = (float*)alloc((size_t)NPAIR * I_DIM * 4);            // 16 MB
    signed char* aq       = (signed char*)alloc((size_t)NPAIR * I_DIM);          // 4 MB
    float*       as_      = (float*)alloc((size_t)NPAIR * 4);
    float*       dnr      = (float*)alloc((size_t)NPAIR * H_DIM * 4);            // 16 MB

    k_router<<<dim3((T_TOK + 255) / 256), dim3(256), 0, stream>>>(rlogits, topk_ids, topk_w);
    k_quant_x<<<dim3(T_TOK), dim3(256), 0, stream>>>(hidden, qx, xs);
    k_dispatch<<<dim3(E_EXP), dim3(64), 0, stream>>>(topk_ids, pair_pos, rows_map, counts);
    k_scan<<<dim3(1), dim3(64), 0, stream>>>(counts, offs);
    k_gemm1<<<dim3(TWOI / NT, CAP / MT, E_EXP), dim3(256), 0, stream>>>(
        qx, xs, gup, gup_s, gup_b, rows_map, counts, offs, act);
    k_quant_act<<<dim3(E_EXP * CAP), dim3(256), 0, stream>>>(act, counts, offs, aq, as_);
    k_gemm2<<<dim3(H_DIM / NT, CAP / MT, E_EXP), dim3(256), 0, stream>>>(
        aq, as_, dnw, dn_s, dn_b, rows_map, counts, offs, dnr);
    k_finalize<<<dim3(T_TOK), dim3(256), 0, stream>>>(dnr, topk_w, pair_pos, out);
}

// Round 2
// 1741.378 us; speedup vs baseline: 1.5300x; 1.0020x over previous
//
#include <hip/hip_runtime.h>
#include <hip/hip_bf16.h>
#include <math.h>

// Problem constants (from reference)
constexpr int E_EXP = 32;
constexpr int TOPK  = 4;
constexpr int H_DIM = 2048;
constexpr int I_DIM = 2048;
constexpr int T_TOK = 512;
constexpr int CAP   = 256;
constexpr int TWOI  = 4096;           // 2*I
constexpr int NPAIR = T_TOK * TOPK;   // 2048
constexpr float ALPHA = 1.702f;
constexpr float LIMIT = 7.0f;

// NOTE (harness contract): integer inputs arrive as int32 per element.
// gate_up_proj / down_proj are int32 arrays of values in [-127,127].

typedef int v4i  __attribute__((ext_vector_type(4)));
typedef int v16i __attribute__((ext_vector_type(16)));

__device__ __forceinline__ float waveReduceMax(float v) {
    #pragma unroll
    for (int off = 32; off > 0; off >>= 1)
        v = fmaxf(v, __shfl_xor(v, off, 64));
    return v;
}

// ---------------------------------------------------------------------------
// Router: softmax + top-4 + renormalize. One thread per token.
// ---------------------------------------------------------------------------
__global__ void k_router(const float* __restrict__ logits,
                         int* __restrict__ topk_ids,
                         float* __restrict__ topk_w) {
    int t = blockIdx.x * blockDim.x + threadIdx.x;
    if (t >= T_TOK) return;
    float l[E_EXP];
    float mx = -1e30f;
    #pragma unroll
    for (int e = 0; e < E_EXP; e++) { l[e] = logits[t * E_EXP + e]; mx = fmaxf(mx, l[e]); }
    #pragma unroll
    for (int e = 0; e < E_EXP; e++) { l[e] = expf(l[e] - mx); }

    float v[TOPK]; int id[TOPK];
    #pragma unroll
    for (int k = 0; k < TOPK; k++) {
        float best = -1.0f; int bi = 0;
        #pragma unroll
        for (int e = 0; e < E_EXP; e++) {
            bool taken = false;
            for (int j = 0; j < k; j++) taken = taken || (id[j] == e);
            if (!taken && l[e] > best) { best = l[e]; bi = e; }
        }
        v[k] = best; id[k] = bi;
    }
    float inv = 1.0f / (v[0] + v[1] + v[2] + v[3]);
    #pragma unroll
    for (int k = 0; k < TOPK; k++) {
        topk_ids[t * TOPK + k] = id[k];
        topk_w[t * TOPK + k]   = v[k] * inv;
    }
}

// ---------------------------------------------------------------------------
// Per-token symmetric int8 dynamic quant of hidden_states. One block per token.
// ---------------------------------------------------------------------------
__global__ void k_quant_x(const float* __restrict__ x,
                          signed char* __restrict__ qx,
                          float* __restrict__ xs) {
    int t = blockIdx.x, tid = threadIdx.x;
    const float4* xr = (const float4*)(x + (size_t)t * H_DIM);
    float4 v0 = xr[tid * 2], v1 = xr[tid * 2 + 1];
    float am = fmaxf(fmaxf(fmaxf(fabsf(v0.x), fabsf(v0.y)), fmaxf(fabsf(v0.z), fabsf(v0.w))),
                     fmaxf(fmaxf(fabsf(v1.x), fabsf(v1.y)), fmaxf(fabsf(v1.z), fabsf(v1.w))));
    __shared__ float red[4];
    am = waveReduceMax(am);
    if ((tid & 63) == 0) red[tid >> 6] = am;
    __syncthreads();
    am = fmaxf(fmaxf(red[0], red[1]), fmaxf(red[2], red[3]));
    float s = am * (1.0f / 127.0f);
    if (tid == 0) xs[t] = s;
    float vv[8] = {v0.x, v0.y, v0.z, v0.w, v1.x, v1.y, v1.z, v1.w};
    int out[2]; signed char* ob = (signed char*)out;
    #pragma unroll
    for (int j = 0; j < 8; j++) {
        float q = (s > 0.f) ? rintf(vv[j] / s) : 0.f;   // bit-match round(x/s)
        q = fminf(127.f, fmaxf(-127.f, q));
        ob[j] = (signed char)q;
    }
    ((int2*)(qx + (size_t)t * H_DIM))[tid] = *(int2*)out;
}

// ---------------------------------------------------------------------------
// Dispatch: exact-order per-expert positions via ballot scan. One wave/expert.
// ---------------------------------------------------------------------------
__global__ void k_dispatch(const int* __restrict__ topk_ids,
                           int* __restrict__ pair_pos,
                           int* __restrict__ rows_map,
                           int* __restrict__ counts) {
    int e = blockIdx.x;
    int lane = threadIdx.x;
    int base = 0;
    unsigned long long lt = (1ull << lane) - 1ull;
    if (lane == 63) lt = 0x7FFFFFFFFFFFFFFFull;
    for (int i0 = 0; i0 < NPAIR; i0 += 64) {
        int idx = i0 + lane;
        int ee = topk_ids[idx];
        bool m = (ee == e);
        unsigned long long mask = __ballot(m);
        int pre = __popcll(mask & lt);
        if (m) {
            int pos = base + pre;
            pair_pos[idx] = pos;
            if (pos < CAP) rows_map[e * CAP + pos] = idx;
        }
        base += __popcll(mask);
    }
    if (lane == 0) counts[e] = (base < CAP) ? base : CAP;
}

// Exclusive scan of 32 counts (single thread — trivial).
__global__ void k_scan(const int* __restrict__ counts, int* __restrict__ offs) {
    if (threadIdx.x == 0 && blockIdx.x == 0) {
        int a = 0;
        for (int e = 0; e < E_EXP; e++) { offs[e] = a; a += counts[e]; }
        offs[E_EXP] = a;
    }
}

// ---------------------------------------------------------------------------
// MFMA grouped GEMM core, v2:
//  - A LDS: [128 rows][80B] (64B data + pad), 16B-chunk XOR swizzle
//    slot = chunk ^ ((row>>3)&3)  -> balanced banks on b128 reads/writes.
//  - B LDS: chunk-major int32 [16 k-chunks][64 cols]; staging is one balanced
//    ds_write_b128/thread; fragment reads are conflict-free ds_read_b32.
//  - Double-buffered LDS, one barrier per K-step; next tile's global loads
//    issued before compute (counted vmcnt keeps them in flight).
//  4 waves = 2x2; each wave: two 32x32x32 i8 MFMA tiles (64 rows x 32 cols).
// ---------------------------------------------------------------------------
#define MT 128
#define NT 64
#define KC 64
#define ASTR 80   // A LDS row stride (bytes)

// GEMM1: [rows,H] x [H,2I] + dequant + bias + swiglu -> act f32 [rows_compact, I]
__global__ __launch_bounds__(256, 4) void k_gemm1(
    const signed char* __restrict__ qx, const float* __restrict__ xs,
    const int* __restrict__ W, const float* __restrict__ wscale,
    const float* __restrict__ wbias, const int* __restrict__ rows_map,
    const int* __restrict__ counts, const int* __restrict__ offs,
    float* __restrict__ act) {
    int e = blockIdx.z;
    int cnt = counts[e];
    int m0 = blockIdx.y * MT;
    if (m0 >= cnt) return;
    int rb = offs[e];
    int n0 = blockIdx.x * NT;
    int tid = threadIdx.x;

    __shared__ __align__(16) signed char a_sm[2][MT * ASTR];
    __shared__ __align__(16) int b_sm[2][16 * 64];
    __shared__ int   tok_lds[MT];
    __shared__ float s_lds[MT];

    if (tid < MT) {
        int r = m0 + tid;
        int tok = 0; float sc = 0.f;
        if (r < cnt) { int pair = rows_map[e * CAP + r]; tok = pair >> 2; sc = xs[tok]; }
        tok_lds[tid] = tok; s_lds[tid] = sc;
    }
    __syncthreads();

    // A staging: 4 threads/row, 16B each; rows arow and arow+64.
    int arow = tid >> 2, ahalf = tid & 3;
    const signed char* ap0 = qx + (size_t)tok_lds[arow]      * H_DIM + ahalf * 16;
    const signed char* ap1 = qx + (size_t)tok_lds[arow + 64] * H_DIM + ahalf * 16;
    int aw_off  = arow * ASTR + ((ahalf ^ ((arow >> 3) & 3)) << 4);
    int aw_off1 = aw_off + 64 * ASTR;

    // B staging: thread (nq,kq) loads 4 k-rows x 4 cols, packs to 4 words.
    int nq = tid & 15, kq = tid >> 4;
    const int* bp = W + (size_t)e * H_DIM * TWOI + (size_t)(kq * 4) * TWOI + n0 + nq * 4;
    int bw_woff = kq * 64 + nq * 4;

    // wave decomposition: 2x2 waves, each 64 rows x 32 cols
    int lane = tid & 63, wv = tid >> 6;
    int wr = wv >> 1, wc = wv & 1;
    int l31 = lane & 31, lhi = lane >> 5;
    int qz = (l31 >> 3) & 3;
    int ar_off  = (wr * 64 + l31) * ASTR;
    int c_off0 = ((lhi) ^ qz) << 4;
    int c_off1 = ((lhi + 2) ^ qz) << 4;
    int br_woff = 256 * lhi + wc * 32 + l31;

    v16i acc0 = {}, acc1 = {};

    // prologue: tile 0 -> buf 0
    int4 va0 = *(const int4*)ap0, va1 = *(const int4*)ap1;
    int4 wv0 = *(const int4*)(bp);
    int4 wv1 = *(const int4*)(bp + TWOI);
    int4 wv2 = *(const int4*)(bp + 2 * TWOI);
    int4 wv3 = *(const int4*)(bp + 3 * TWOI);
    ap0 += KC; ap1 += KC; bp += (size_t)KC * TWOI;
    *(int4*)(a_sm[0] + aw_off)  = va0;
    *(int4*)(a_sm[0] + aw_off1) = va1;
    {
        v4i pk = { (wv0.x & 255) | ((wv1.x & 255) << 8) | ((wv2.x & 255) << 16) | (wv3.x << 24),
                   (wv0.y & 255) | ((wv1.y & 255) << 8) | ((wv2.y & 255) << 16) | (wv3.y << 24),
                   (wv0.z & 255) | ((wv1.z & 255) << 8) | ((wv2.z & 255) << 16) | (wv3.z << 24),
                   (wv0.w & 255) | ((wv1.w & 255) << 8) | ((wv2.w & 255) << 16) | (wv3.w << 24) };
        *(v4i*)(b_sm[0] + bw_woff) = pk;
    }
    __syncthreads();

    constexpr int NSTEP = H_DIM / KC;   // 32
    for (int t = 0; t < NSTEP; ++t) {
        int cur = t & 1;
        bool more = (t + 1 < NSTEP);
        if (more) {           // issue next tile's global loads (stay in flight)
            va0 = *(const int4*)ap0; va1 = *(const int4*)ap1;
            wv0 = *(const int4*)(bp);
            wv1 = *(const int4*)(bp + TWOI);
            wv2 = *(const int4*)(bp + 2 * TWOI);
            wv3 = *(const int4*)(bp + 3 * TWOI);
            ap0 += KC; ap1 += KC; bp += (size_t)KC * TWOI;
        }
        const signed char* aA = a_sm[cur] + ar_off;
        const int* bB = b_sm[cur] + br_woff;
        #pragma unroll
        for (int kk = 0; kk < 2; ++kk) {
            int coff = kk ? c_off1 : c_off0;
            v4i a0 = *(const v4i*)(aA + coff);
            v4i a1 = *(const v4i*)(aA + 32 * ASTR + coff);
            v4i bf = { bB[512 * kk], bB[512 * kk + 64], bB[512 * kk + 128], bB[512 * kk + 192] };
            acc0 = __builtin_amdgcn_mfma_i32_32x32x32_i8(a0, bf, acc0, 0, 0, 0);
            acc1 = __builtin_amdgcn_mfma_i32_32x32x32_i8(a1, bf, acc1, 0, 0, 0);
        }
        if (more) {
            int nb = cur ^ 1;
            *(int4*)(a_sm[nb] + aw_off)  = va0;
            *(int4*)(a_sm[nb] + aw_off1) = va1;
            v4i pk = { (wv0.x & 255) | ((wv1.x & 255) << 8) | ((wv2.x & 255) << 16) | (wv3.x << 24),
                       (wv0.y & 255) | ((wv1.y & 255) << 8) | ((wv2.y & 255) << 16) | (wv3.y << 24),
                       (wv0.z & 255) | ((wv1.z & 255) << 8) | ((wv2.z & 255) << 16) | (wv3.z << 24),
                       (wv0.w & 255) | ((wv1.w & 255) << 8) | ((wv2.w & 255) << 16) | (wv3.w << 24) };
            *(v4i*)(b_sm[nb] + bw_woff) = pk;
        }
        __syncthreads();
    }

    // epilogue: dequant + bias + swiglu (interleaved cols), write act f32.
    // C/D layout (32x32): col = lane&31, row = (reg&3) + 8*(reg>>2) + 4*(lane>>5)
    int c = n0 + wc * 32 + l31;
    float wsc = wscale[e * TWOI + c];
    float wbs = wbias[e * TWOI + c];
    bool evenc = (l31 & 1) == 0;
    #pragma unroll
    for (int i = 0; i < 2; i++) {
        #pragma unroll
        for (int reg = 0; reg < 16; reg++) {
            int row_local = wr * 64 + i * 32 + (reg & 3) + 8 * (reg >> 2) + 4 * lhi;
            int accv = (i == 0) ? acc0[reg] : acc1[reg];
            float val = (float)accv * s_lds[row_local] * wsc + wbs;
            float other = __shfl_xor(val, 1, 64);     // partner column (c^1)
            int r = m0 + row_local;
            if (evenc && r < cnt) {
                float g   = fminf(val, LIMIT);
                float lin = fminf(fmaxf(other, -LIMIT), LIMIT);
                float sig = 1.0f / (1.0f + expf(-ALPHA * g));
                act[(size_t)(rb + r) * I_DIM + (c >> 1)] = g * sig * (lin + 1.0f);
            }
        }
    }
}

// Per-row requant of act (compact rows). One block per (e, cap-slot).
__global__ void k_quant_act(const float* __restrict__ act,
                            const int* __restrict__ counts,
                            const int* __restrict__ offs,
                            signed char* __restrict__ aq,
                            float* __restrict__ as_) {
    int e = blockIdx.x / CAP, p = blockIdx.x % CAP;
    if (p >= counts[e]) return;
    int row = offs[e] + p;
    int tid = threadIdx.x;
    const float4* xr = (const float4*)(act + (size_t)row * I_DIM);
    float4 v0 = xr[tid * 2], v1 = xr[tid * 2 + 1];
    float am = fmaxf(fmaxf(fmaxf(fabsf(v0.x), fabsf(v0.y)), fmaxf(fabsf(v0.z), fabsf(v0.w))),
                     fmaxf(fmaxf(fabsf(v1.x), fabsf(v1.y)), fmaxf(fabsf(v1.z), fabsf(v1.w))));
    __shared__ float red[4];
    am = waveReduceMax(am);
    if ((tid & 63) == 0) red[tid >> 6] = am;
    __syncthreads();
    am = fmaxf(fmaxf(red[0], red[1]), fmaxf(red[2], red[3]));
    float s = am * (1.0f / 127.0f);
    if (tid == 0) as_[row] = s;
    float vv[8] = {v0.x, v0.y, v0.z, v0.w, v1.x, v1.y, v1.z, v1.w};
    int out[2]; signed char* ob = (signed char*)out;
    #pragma unroll
    for (int j = 0; j < 8; j++) {
        float q = (s > 0.f) ? rintf(vv[j] / s) : 0.f;
        q = fminf(127.f, fmaxf(-127.f, q));
        ob[j] = (signed char)q;
    }
    ((int2*)(aq + (size_t)row * I_DIM))[tid] = *(int2*)out;
}

// GEMM2: [rows,I] x [I,H] + dequant + bias -> dn_rows f32 [NPAIR, H]
__global__ __launch_bounds__(256, 4) void k_gemm2(
    const signed char* __restrict__ aq, const float* __restrict__ as_,
    const int* __restrict__ W, const float* __restrict__ wscale,
    const float* __restrict__ wbias, const int* __restrict__ rows_map,
    const int* __restrict__ counts, const int* __restrict__ offs,
    float* __restrict__ dn_rows) {
    int e = blockIdx.z;
    int cnt = counts[e];
    int m0 = blockIdx.y * MT;
    if (m0 >= cnt) return;
    int rb = offs[e];
    int n0 = blockIdx.x * NT;
    int tid = threadIdx.x;

    __shared__ __align__(16) signed char a_sm[2][MT * ASTR];
    __shared__ __align__(16) int b_sm[2][16 * 64];
    __shared__ int   src_lds[MT];
    __shared__ int   pair_lds[MT];
    __shared__ float s_lds[MT];

    if (tid < MT) {
        int r = m0 + tid;
        int src = rb; int pr = 0; float sc = 0.f;
        if (r < cnt) { src = rb + r; pr = rows_map[e * CAP + r]; sc = as_[rb + r]; }
        src_lds[tid] = src; pair_lds[tid] = pr; s_lds[tid] = sc;
    }
    __syncthreads();

    int arow = tid >> 2, ahalf = tid & 3;
    const signed char* ap0 = aq + (size_t)src_lds[arow]      * I_DIM + ahalf * 16;
    const signed char* ap1 = aq + (size_t)src_lds[arow + 64] * I_DIM + ahalf * 16;
    int aw_off  = arow * ASTR + ((ahalf ^ ((arow >> 3) & 3)) << 4);
    int aw_off1 = aw_off + 64 * ASTR;

    int nq = tid & 15, kq = tid >> 4;
    const int* bp = W + (size_t)e * I_DIM * H_DIM + (size_t)(kq * 4) * H_DIM + n0 + nq * 4;
    int bw_woff = kq * 64 + nq * 4;

    int lane = tid & 63, wv = tid >> 6;
    int wr = wv >> 1, wc = wv & 1;
    int l31 = lane & 31, lhi = lane >> 5;
    int qz = (l31 >> 3) & 3;
    int ar_off  = (wr * 64 + l31) * ASTR;
    int c_off0 = ((lhi) ^ qz) << 4;
    int c_off1 = ((lhi + 2) ^ qz) << 4;
    int br_woff = 256 * lhi + wc * 32 + l31;

    v16i acc0 = {}, acc1 = {};

    int4 va0 = *(const int4*)ap0, va1 = *(const int4*)ap1;
    int4 wv0 = *(const int4*)(bp);
    int4 wv1 = *(const int4*)(bp + H_DIM);
    int4 wv2 = *(const int4*)(bp + 2 * H_DIM);
    int4 wv3 = *(const int4*)(bp + 3 * H_DIM);
    ap0 += KC; ap1 += KC; bp += (size_t)KC * H_DIM;
    *(int4*)(a_sm[0] + aw_off)  = va0;
    *(int4*)(a_sm[0] + aw_off1) = va1;
    {
        v4i pk = { (wv0.x & 255) | ((wv1.x & 255) << 8) | ((wv2.x & 255) << 16) | (wv3.x << 24),
                   (wv0.y & 255) | ((wv1.y & 255) << 8) | ((wv2.y & 255) << 16) | (wv3.y << 24),
                   (wv0.z & 255) | ((wv1.z & 255) << 8) | ((wv2.z & 255) << 16) | (wv3.z << 24),
                   (wv0.w & 255) | ((wv1.w & 255) << 8) | ((wv2.w & 255) << 16) | (wv3.w << 24) };
        *(v4i*)(b_sm[0] + bw_woff) = pk;
    }
    __syncthreads();

    constexpr int NSTEP = I_DIM / KC;   // 32
    for (int t = 0; t < NSTEP; ++t) {
        int cur = t & 1;
        bool more = (t + 1 < NSTEP);
        if (more) {
            va0 = *(const int4*)ap0; va1 = *(const int4*)ap1;
            wv0 = *(const int4*)(bp);
            wv1 = *(const int4*)(bp + H_DIM);
            wv2 = *(const int4*)(bp + 2 * H_DIM);
            wv3 = *(const int4*)(bp + 3 * H_DIM);
            ap0 += KC; ap1 += KC; bp += (size_t)KC * H_DIM;
        }
        const signed char* aA = a_sm[cur] + ar_off;
        const int* bB = b_sm[cur] + br_woff;
        #pragma unroll
        for (int kk = 0; kk < 2; ++kk) {
            int coff = kk ? c_off1 : c_off0;
            v4i a0 = *(const v4i*)(aA + coff);
            v4i a1 = *(const v4i*)(aA + 32 * ASTR + coff);
            v4i bf = { bB[512 * kk], bB[512 * kk + 64], bB[512 * kk + 128], bB[512 * kk + 192] };
            acc0 = __builtin_amdgcn_mfma_i32_32x32x32_i8(a0, bf, acc0, 0, 0, 0);
            acc1 = __builtin_amdgcn_mfma_i32_32x32x32_i8(a1, bf, acc1, 0, 0, 0);
        }
        if (more) {
            int nb = cur ^ 1;
            *(int4*)(a_sm[nb] + aw_off)  = va0;
            *(int4*)(a_sm[nb] + aw_off1) = va1;
            v4i pk = { (wv0.x & 255) | ((wv1.x & 255) << 8) | ((wv2.x & 255) << 16) | (wv3.x << 24),
                       (wv0.y & 255) | ((wv1.y & 255) << 8) | ((wv2.y & 255) << 16) | (wv3.y << 24),
                       (wv0.z & 255) | ((wv1.z & 255) << 8) | ((wv2.z & 255) << 16) | (wv3.z << 24),
                       (wv0.w & 255) | ((wv1.w & 255) << 8) | ((wv2.w & 255) << 16) | (wv3.w << 24) };
            *(v4i*)(b_sm[nb] + bw_woff) = pk;
        }
        __syncthreads();
    }

    int c = n0 + wc * 32 + l31;
    float wsc = wscale[e * H_DIM + c];
    float wbs = wbias[e * H_DIM + c];
    #pragma unroll
    for (int i = 0; i < 2; i++) {
        #pragma unroll
        for (int reg = 0; reg < 16; reg++) {
            int row_local = wr * 64 + i * 32 + (reg & 3) + 8 * (reg >> 2) + 4 * lhi;
            int r = m0 + row_local;
            if (r < cnt) {
                int accv = (i == 0) ? acc0[reg] : acc1[reg];
                float val = (float)accv * s_lds[row_local] * wsc + wbs;
                dn_rows[(size_t)pair_lds[row_local] * H_DIM + c] = val;
            }
        }
    }
}

// Finalize: out[t] = sum_k w[t,k] * dn_rows[t*K+k] (valid only). Block per token.
__global__ void k_finalize(const float* __restrict__ dn_rows,
                           const float* __restrict__ topk_w,
                           const int* __restrict__ pair_pos,
                           float* __restrict__ out) {
    int t = blockIdx.x, tid = threadIdx.x;
    int h = tid * 8;
    float acc[8] = {0, 0, 0, 0, 0, 0, 0, 0};
    #pragma unroll
    for (int k = 0; k < TOPK; k++) {
        int pair = t * TOPK + k;
        if (pair_pos[pair] < CAP) {
            float w = topk_w[pair];
            const float4* dr = (const float4*)(dn_rows + (size_t)pair * H_DIM + h);
            float4 d0 = dr[0], d1 = dr[1];
            acc[0] += w * d0.x; acc[1] += w * d0.y; acc[2] += w * d0.z; acc[3] += w * d0.w;
            acc[4] += w * d1.x; acc[5] += w * d1.y; acc[6] += w * d1.z; acc[7] += w * d1.w;
        }
    }
    float4* o = (float4*)(out + (size_t)t * H_DIM + h);
    o[0] = make_float4(acc[0], acc[1], acc[2], acc[3]);
    o[1] = make_float4(acc[4], acc[5], acc[6], acc[7]);
}

// ---------------------------------------------------------------------------
extern "C" void kernel_launch(void* const* d_in, const int* in_sizes, int n_in,
                              void* d_out, int out_size, void* d_ws, size_t ws_size,
                              hipStream_t stream) {
    const float* hidden  = (const float*)d_in[0];
    const float* rlogits = (const float*)d_in[1];
    const int*   gup     = (const int*)d_in[2];    // int8 values stored as int32
    const float* gup_s   = (const float*)d_in[3];
    const float* gup_b   = (const float*)d_in[4];
    const int*   dnw     = (const int*)d_in[5];    // int8 values stored as int32
    const float* dn_s    = (const float*)d_in[6];
    const float* dn_b    = (const float*)d_in[7];
    float*       out     = (float*)d_out;

    char* ws = (char*)d_ws;
    size_t off = 0;
    auto alloc = [&](size_t bytes) -> void* {
        void* p = ws + off;
        off = (off + bytes + 255) & ~(size_t)255;
        return p;
    };
    signed char* qx       = (signed char*)alloc((size_t)T_TOK * H_DIM);          // 1 MB
    float*       xs       = (float*)alloc((size_t)T_TOK * 4);
    int*         topk_ids = (int*)alloc((size_t)NPAIR * 4);
    float*       topk_w   = (float*)alloc((size_t)NPAIR * 4);
    int*         pair_pos = (int*)alloc((size_t)NPAIR * 4);
    int*         rows_map = (int*)alloc((size_t)E_EXP * CAP * 4);
    int*         counts   = (int*)alloc((size_t)E_EXP * 4);
    int*         offs     = (int*)alloc((size_t)(E_EXP + 1) * 4);
    float*       act      = (float*)alloc((size_t)NPAIR * I_DIM * 4);            // 16 MB
    signed char* aq       = (signed char*)alloc((size_t)NPAIR * I_DIM);          // 4 MB
    float*       as_      = (float*)alloc((size_t)NPAIR * 4);
    float*       dnr      = (float*)alloc((size_t)NPAIR * H_DIM * 4);            // 16 MB

    k_router<<<dim3((T_TOK + 255) / 256), dim3(256), 0, stream>>>(rlogits, topk_ids, topk_w);
    k_quant_x<<<dim3(T_TOK), dim3(256), 0, stream>>>(hidden, qx, xs);
    k_dispatch<<<dim3(E_EXP), dim3(64), 0, stream>>>(topk_ids, pair_pos, rows_map, counts);
    k_scan<<<dim3(1), dim3(64), 0, stream>>>(counts, offs);
    k_gemm1<<<dim3(TWOI / NT, CAP / MT, E_EXP), dim3(256), 0, stream>>>(
        qx, xs, gup, gup_s, gup_b, rows_map, counts, offs, act);
    k_quant_act<<<dim3(E_EXP * CAP), dim3(256), 0, stream>>>(act, counts, offs, aq, as_);
    k_gemm2<<<dim3(H_DIM / NT, CAP / MT, E_EXP), dim3(256), 0, stream>>>(
        aq, as_, dnw, dn_s, dn_b, rows_map, counts, offs, dnr);
    k_finalize<<<dim3(T_TOK), dim3(256), 0, stream>>>(dnr, topk_w, pair_pos, out);
}